// Round 1
// baseline (1000.879 us; speedup 1.0000x reference)
//
#include <hip/hip_runtime.h>

#define NN 20000
#define KK 32
#define DD 128
#define NEGV (-1e9f)

__global__ __launch_bounds__(128) void ppagg_kernel(
    const int* __restrict__ nodes,
    const int* __restrict__ neigh,
    const int* __restrict__ degrees,
    const float* __restrict__ u2e,
    const float* __restrict__ W1,
    const float* __restrict__ b1,
    const float* __restrict__ W2,
    const float* __restrict__ b2,
    const float* __restrict__ W3,
    const float* __restrict__ b3,
    float* __restrict__ out)
{
    const int n = blockIdx.x;
    const int d = threadIdx.x;   // 0..127

    __shared__ __align__(16) float s_e[KK][DD];   // neighbor embeddings, 16 KB
    __shared__ __align__(16) float s_x[DD];       // self embedding
    __shared__ __align__(16) float s_h[KK][DD];   // h1, then h2*W3 products, 16 KB
    __shared__ float s_part[4][KK];
    __shared__ float s_att[KK];

    const int node = nodes[n];
    const float4* __restrict__ u4 = (const float4*)u2e;

    // ---- gather self + 32 neighbors into LDS (float4, coalesced) ----
    {
        const int kk = d >> 5;    // which of 4 rows this thread helps load
        const int c  = d & 31;    // float4 column within row
        #pragma unroll
        for (int k0 = 0; k0 < KK; k0 += 4) {
            const int idx = neigh[n * KK + k0 + kk];
            ((float4*)s_e)[(k0 + kk) * 32 + c] = u4[(long)idx * 32 + c];
        }
        if (d < 32) ((float4*)s_x)[d] = u4[(long)node * 32 + d];
    }
    __syncthreads();

    // ---- layer 1: h1[k][d] = relu( e[k]·W1[:128,d] + self·W1[128:,d] + b1[d] )
    // self half is identical for all k -> compute once
    float sd = b1[d];
    #pragma unroll 8
    for (int i = 0; i < DD; i += 4) {
        const float4 xv = *(const float4*)&s_x[i];
        sd = fmaf(xv.x, W1[(DD + i    ) * DD + d], sd);
        sd = fmaf(xv.y, W1[(DD + i + 1) * DD + d], sd);
        sd = fmaf(xv.z, W1[(DD + i + 2) * DD + d], sd);
        sd = fmaf(xv.w, W1[(DD + i + 3) * DD + d], sd);
    }

    float acc[KK];
    #pragma unroll
    for (int k = 0; k < KK; ++k) acc[k] = sd;
    for (int i = 0; i < DD; i += 4) {          // each W1 value amortized over 32 k
        const float w0 = W1[(i    ) * DD + d];
        const float w1 = W1[(i + 1) * DD + d];
        const float w2 = W1[(i + 2) * DD + d];
        const float w3 = W1[(i + 3) * DD + d];
        #pragma unroll
        for (int k = 0; k < KK; ++k) {
            const float4 ev = *(const float4*)&s_e[k][i];   // wave-uniform broadcast
            acc[k] = fmaf(ev.x, w0, acc[k]);
            acc[k] = fmaf(ev.y, w1, acc[k]);
            acc[k] = fmaf(ev.z, w2, acc[k]);
            acc[k] = fmaf(ev.w, w3, acc[k]);
        }
    }
    #pragma unroll
    for (int k = 0; k < KK; ++k) s_h[k][d] = fmaxf(acc[k], 0.f);
    __syncthreads();

    // ---- layer 2: h2[k][d] = relu( h1[k]·W2[:,d] + b2[d] )
    float acc2[KK];
    const float b2d = b2[d];
    #pragma unroll
    for (int k = 0; k < KK; ++k) acc2[k] = b2d;
    for (int j = 0; j < DD; j += 4) {
        const float w0 = W2[(j    ) * DD + d];
        const float w1 = W2[(j + 1) * DD + d];
        const float w2v = W2[(j + 2) * DD + d];
        const float w3v = W2[(j + 3) * DD + d];
        #pragma unroll
        for (int k = 0; k < KK; ++k) {
            const float4 hv = *(const float4*)&s_h[k][j];
            acc2[k] = fmaf(hv.x, w0, acc2[k]);
            acc2[k] = fmaf(hv.y, w1, acc2[k]);
            acc2[k] = fmaf(hv.z, w2v, acc2[k]);
            acc2[k] = fmaf(hv.w, w3v, acc2[k]);
        }
    }
    __syncthreads();   // all layer-2 reads of s_h done before overwrite

    // ---- layer 3 products: s_h[k][d] = h2[k][d] * W3[d]
    const float w3d = W3[d];
    #pragma unroll
    for (int k = 0; k < KK; ++k) s_h[k][d] = fmaxf(acc2[k], 0.f) * w3d;
    __syncthreads();

    // ---- logits: partial-reduce 128 products per k across 4 thread-groups
    {
        const int k = d & 31, q = d >> 5;
        const float4* hp = (const float4*)&s_h[k][q * 32];
        float p = 0.f;
        #pragma unroll
        for (int c = 0; c < 8; ++c) { const float4 v = hp[c]; p += (v.x + v.y) + (v.z + v.w); }
        s_part[q][k] = p;
    }
    __syncthreads();

    const int deg = degrees[n];

    // ---- masked softmax over 32 neighbors (lanes 0..31 of wave 0)
    if (d < KK) {
        const int k = d;
        const float logit = s_part[0][k] + s_part[1][k] + s_part[2][k] + s_part[3][k] + b3[0];
        const float ml = (k < deg) ? logit : NEGV;
        float m = ml;
        #pragma unroll
        for (int off = 16; off > 0; off >>= 1) m = fmaxf(m, __shfl_xor(m, off, 32));
        const float e = expf(ml - m);
        float ssum = e;
        #pragma unroll
        for (int off = 16; off > 0; off >>= 1) ssum += __shfl_xor(ssum, off, 32);
        s_att[k] = e / ssum;
    }
    __syncthreads();

    // ---- attention-weighted aggregation + residual
    float agg = 0.f;
    #pragma unroll
    for (int k = 0; k < KK; ++k) agg = fmaf(s_att[k], s_e[k][d], agg);
    const float selfv = s_x[d];
    out[(long)n * DD + d] = (deg > 0) ? 0.5f * (agg + selfv) : selfv;
}

extern "C" void kernel_launch(void* const* d_in, const int* in_sizes, int n_in,
                              void* d_out, int out_size, void* d_ws, size_t ws_size,
                              hipStream_t stream) {
    const int*   nodes   = (const int*)d_in[0];
    const int*   neigh   = (const int*)d_in[1];
    const int*   degrees = (const int*)d_in[2];
    const float* u2e     = (const float*)d_in[3];
    const float* W1      = (const float*)d_in[4];
    const float* b1      = (const float*)d_in[5];
    const float* W2      = (const float*)d_in[6];
    const float* b2      = (const float*)d_in[7];
    const float* W3      = (const float*)d_in[8];
    const float* b3      = (const float*)d_in[9];
    float* out = (float*)d_out;

    const int n_nodes = in_sizes[0];   // N = 20000
    ppagg_kernel<<<n_nodes, DD, 0, stream>>>(nodes, neigh, degrees, u2e,
                                             W1, b1, W2, b2, W3, b3, out);
}

// Round 3
// 235.751 us; speedup vs baseline: 4.2455x; 4.2455x over previous
//
#include <hip/hip_runtime.h>
#include <hip/hip_bf16.h>

#define KK 32
#define DD 128
#define NEGV (-1e9f)
#define SE 136   // s_eh row stride in ushorts: 272 B, 16-B aligned, non-pow2 banks

typedef __attribute__((ext_vector_type(8))) short bf16x8;
typedef __attribute__((ext_vector_type(8))) unsigned short u16x8;
typedef __attribute__((ext_vector_type(4))) float f32x4;

__device__ __forceinline__ unsigned short f2bf(float f) {
    union { float f; unsigned u; } v; v.f = f;
    unsigned r = v.u + 0x7fffu + ((v.u >> 16) & 1u);   // RNE
    return (unsigned short)(r >> 16);
}
__device__ __forceinline__ float bf2f(unsigned short h) {
    union { unsigned u; float f; } v; v.u = ((unsigned)h) << 16;
    return v.f;
}
// packed f32x2 -> bf16x2 (v_cvt_pk_bf16_f32), RNE
__device__ __forceinline__ unsigned pk2(float x, float y) {
    union { __hip_bfloat162 h; unsigned u; } c;
    c.h = __float22bfloat162_rn(float2{x, y});
    return c.u;
}

// ---- prep: W1[256x128] -> W1t bf16 [n][k] (128x256); W2[128x128] -> W2t bf16 [n][k] ----
__global__ __launch_bounds__(256) void prep_kernel(const float* __restrict__ W1,
                                                   const float* __restrict__ W2,
                                                   unsigned short* __restrict__ W1t,
                                                   unsigned short* __restrict__ W2t) {
    const int id = blockIdx.x * 256 + threadIdx.x;   // 0 .. 49151
    if (id < 256 * 128) {
        const int n = id >> 8, k = id & 255;
        W1t[id] = f2bf(W1[k * DD + n]);
    } else {
        const int j = id - 256 * 128;
        const int n = j >> 7, k = j & 127;
        W2t[j] = f2bf(W2[k * DD + n]);
    }
}

__global__ __launch_bounds__(256, 2) void ppagg_mfma(
    const int* __restrict__ nodes, const int* __restrict__ neigh,
    const int* __restrict__ degrees, const float* __restrict__ u2e,
    const unsigned short* __restrict__ W1t, const unsigned short* __restrict__ W2t,
    const float* __restrict__ b1, const float* __restrict__ b2,
    const float* __restrict__ W3, const float* __restrict__ b3,
    float* __restrict__ out, const int Nn)
{
    __shared__ __align__(16) unsigned short s_eh[128 * SE];  // 34816 B: e-tile, then h1, then h2
    __shared__ __align__(16) unsigned short s_x[4 * DD];     // self vectors bf16
    __shared__ __align__(16) float s_xf[4 * DD];             // self vectors fp32 (epilogue)
    __shared__ float s_w3[DD];
    __shared__ float s_att[128];
    __shared__ int   s_idx[128];

    const int tid  = threadIdx.x;
    const int w    = tid >> 6;     // wave id
    const int lane = tid & 63;
    const int ln   = lane & 15;
    const int q    = lane >> 4;    // quad

    if (tid < DD) s_w3[tid] = W3[tid];

    // ---- weight fragments in registers (loaded once) ----
    // B-frag (16x16x32): B[k = q*8+j][n = ln]; W1t/W2t are [n][k] -> contiguous 16 B reads
    bf16x8 b1f[8][2], b2f[4][2];
    float b1c[2], b2c[2];
    #pragma unroll
    for (int nt = 0; nt < 2; ++nt) {
        const int c = w * 32 + nt * 16 + ln;
        #pragma unroll
        for (int kk = 0; kk < 8; ++kk)
            b1f[kk][nt] = *(const bf16x8*)(W1t + c * 256 + kk * 32 + q * 8);
        #pragma unroll
        for (int kk = 0; kk < 4; ++kk)
            b2f[kk][nt] = *(const bf16x8*)(W2t + c * 128 + kk * 32 + q * 8);
        b1c[nt] = b1[c];
        b2c[nt] = b2[c];
    }

    const int nodes_base = blockIdx.x * 8;

    for (int it = 0; it < 2; ++it) {
        const int gbase = nodes_base + it * 4;   // rows 0..127 = (g=row>>5, k=row&31)

        // ---------- stage: 128 neighbor rows fp32 -> bf16 LDS (full 64-el half per thread) ----------
        {
            const int r = tid & 127;
            const int h = tid >> 7;          // col half (0: 0..63, 1: 64..127)
            int ng = gbase + (r >> 5);
            if (ng >= Nn) ng = Nn - 1;
            const int idx = neigh[ng * KK + (r & 31)];
            if (h == 0) s_idx[r] = idx;
            const float4* src = (const float4*)(u2e + (long)idx * DD + h * 64);
            unsigned short* dst = s_eh + r * SE + h * 64;
            #pragma unroll
            for (int c8 = 0; c8 < 8; ++c8) {   // 8 x (2 float4 -> 8 bf16)
                const float4 v0 = src[c8 * 2];
                const float4 v1 = src[c8 * 2 + 1];
                uint4 p;
                p.x = pk2(v0.x, v0.y); p.y = pk2(v0.z, v0.w);
                p.z = pk2(v1.x, v1.y); p.w = pk2(v1.z, v1.w);
                *(uint4*)(dst + c8 * 8) = p;
            }
            // selves: wave w stages node gbase+w
            int ngs = gbase + w;
            if (ngs >= Nn) ngs = Nn - 1;
            const int snode = nodes[ngs];
            const float2 sv = *(const float2*)(u2e + (long)snode * DD + lane * 2);
            *(float2*)(s_xf + w * DD + lane * 2) = sv;
            *(unsigned*)(s_x + w * DD + lane * 2) = pk2(sv.x, sv.y);
        }
        __syncthreads();

        // ---------- layer 1: C[128x128] = concat(e, self)[128x256] x W1 ----------
        f32x4 acc[8][2];
        #pragma unroll
        for (int mt = 0; mt < 8; ++mt) {
            acc[mt][0] = (f32x4){0.f, 0.f, 0.f, 0.f};
            acc[mt][1] = (f32x4){0.f, 0.f, 0.f, 0.f};
        }
        #pragma unroll
        for (int kk = 0; kk < 4; ++kk) {              // e-half of the concat
            bf16x8 a[8];
            #pragma unroll
            for (int mt = 0; mt < 8; ++mt)
                a[mt] = *(const bf16x8*)(s_eh + (mt * 16 + ln) * SE + kk * 32 + q * 8);
            #pragma unroll
            for (int mt = 0; mt < 8; ++mt) {
                acc[mt][0] = __builtin_amdgcn_mfma_f32_16x16x32_bf16(a[mt], b1f[kk][0], acc[mt][0], 0, 0, 0);
                acc[mt][1] = __builtin_amdgcn_mfma_f32_16x16x32_bf16(a[mt], b1f[kk][1], acc[mt][1], 0, 0, 0);
            }
        }
        #pragma unroll
        for (int kk = 4; kk < 8; ++kk) {              // self-half: broadcast row (g = mt>>1)
            #pragma unroll
            for (int mt = 0; mt < 8; ++mt) {
                const bf16x8 a = *(const bf16x8*)(s_x + (mt >> 1) * DD + (kk - 4) * 32 + q * 8);
                acc[mt][0] = __builtin_amdgcn_mfma_f32_16x16x32_bf16(a, b1f[kk][0], acc[mt][0], 0, 0, 0);
                acc[mt][1] = __builtin_amdgcn_mfma_f32_16x16x32_bf16(a, b1f[kk][1], acc[mt][1], 0, 0, 0);
            }
        }
        __syncthreads();    // e-tile reads done; s_eh reused for h1

        // h1 = relu(acc + b1) -> bf16 -> s_eh (C-layout: row = mt*16 + q*4 + r, col = w*32+nt*16+ln)
        #pragma unroll
        for (int mt = 0; mt < 8; ++mt)
            #pragma unroll
            for (int nt = 0; nt < 2; ++nt) {
                const int c = w * 32 + nt * 16 + ln;
                #pragma unroll
                for (int r = 0; r < 4; ++r) {
                    const int row = mt * 16 + q * 4 + r;
                    s_eh[row * SE + c] = f2bf(fmaxf(acc[mt][nt][r] + b1c[nt], 0.f));
                }
            }
        __syncthreads();

        // ---------- layer 2: C2[128x128] = h1 x W2 ----------
        f32x4 acc2[8][2];
        #pragma unroll
        for (int mt = 0; mt < 8; ++mt) {
            acc2[mt][0] = (f32x4){0.f, 0.f, 0.f, 0.f};
            acc2[mt][1] = (f32x4){0.f, 0.f, 0.f, 0.f};
        }
        #pragma unroll
        for (int kk = 0; kk < 4; ++kk) {
            bf16x8 a[8];
            #pragma unroll
            for (int mt = 0; mt < 8; ++mt)
                a[mt] = *(const bf16x8*)(s_eh + (mt * 16 + ln) * SE + kk * 32 + q * 8);
            #pragma unroll
            for (int mt = 0; mt < 8; ++mt) {
                acc2[mt][0] = __builtin_amdgcn_mfma_f32_16x16x32_bf16(a[mt], b2f[kk][0], acc2[mt][0], 0, 0, 0);
                acc2[mt][1] = __builtin_amdgcn_mfma_f32_16x16x32_bf16(a[mt], b2f[kk][1], acc2[mt][1], 0, 0, 0);
            }
        }
        __syncthreads();    // h1 reads done

        // h2 = relu(acc2 + b2) -> bf16 -> s_eh
        #pragma unroll
        for (int mt = 0; mt < 8; ++mt)
            #pragma unroll
            for (int nt = 0; nt < 2; ++nt) {
                const int c = w * 32 + nt * 16 + ln;
                #pragma unroll
                for (int r = 0; r < 4; ++r) {
                    const int row = mt * 16 + q * 4 + r;
                    s_eh[row * SE + c] = f2bf(fmaxf(acc2[mt][nt][r] + b2c[nt], 0.f));
                }
            }
        __syncthreads();

        // ---------- logits + masked softmax (threads 0..127; shfl masks < 32 stay in-group) ----------
        if (tid < 128) {
            const int row = tid;
            const unsigned short* hp = s_eh + row * SE;
            float dot = 0.f;
            #pragma unroll
            for (int c8 = 0; c8 < 16; ++c8) {
                const u16x8 hv = *(const u16x8*)(hp + c8 * 8);
                #pragma unroll
                for (int j = 0; j < 8; ++j)
                    dot = fmaf(bf2f(hv[j]), s_w3[c8 * 8 + j], dot);
            }
            const float logit = dot + b3[0];
            int ng = gbase + (row >> 5);
            if (ng >= Nn) ng = Nn - 1;
            const int deg = degrees[ng];
            const float ml = ((row & 31) < deg) ? logit : NEGV;
            float mx = ml;
            #pragma unroll
            for (int off = 16; off > 0; off >>= 1) mx = fmaxf(mx, __shfl_xor(mx, off));
            const float e = __expf(ml - mx);
            float ssum = e;
            #pragma unroll
            for (int off = 16; off > 0; off >>= 1) ssum += __shfl_xor(ssum, off);
            s_att[row] = e / ssum;
        }
        __syncthreads();

        // ---------- epilogue: fp32 attention-weighted aggregation (wave w -> node gbase+w) ----------
        {
            const int ng = gbase + w;
            const int d0 = lane * 2;
            float ax = 0.f, ay = 0.f;
            #pragma unroll 8
            for (int k = 0; k < KK; ++k) {
                const int   ridx = s_idx[w * KK + k];
                const float a    = s_att[w * KK + k];
                const float2 ev  = *(const float2*)(u2e + (long)ridx * DD + d0);
                ax = fmaf(a, ev.x, ax);
                ay = fmaf(a, ev.y, ay);
            }
            if (ng < Nn) {
                const int deg = degrees[ng];
                const float sx = s_xf[w * DD + d0];
                const float sy = s_xf[w * DD + d0 + 1];
                float2 o;
                o.x = (deg > 0) ? 0.5f * (ax + sx) : sx;
                o.y = (deg > 0) ? 0.5f * (ay + sy) : sy;
                *(float2*)(out + (long)ng * DD + d0) = o;
            }
        }
        __syncthreads();   // s_att/s_idx/s_xf consumed before next iteration's staging
    }
}

extern "C" void kernel_launch(void* const* d_in, const int* in_sizes, int n_in,
                              void* d_out, int out_size, void* d_ws, size_t ws_size,
                              hipStream_t stream) {
    const int*   nodes   = (const int*)d_in[0];
    const int*   neigh   = (const int*)d_in[1];
    const int*   degrees = (const int*)d_in[2];
    const float* u2e     = (const float*)d_in[3];
    const float* W1      = (const float*)d_in[4];
    const float* b1      = (const float*)d_in[5];
    const float* W2      = (const float*)d_in[6];
    const float* b2      = (const float*)d_in[7];
    const float* W3      = (const float*)d_in[8];
    const float* b3      = (const float*)d_in[9];
    float* out = (float*)d_out;

    unsigned short* W1t = (unsigned short*)d_ws;        // 128*256 bf16 = 64 KB
    unsigned short* W2t = W1t + 256 * 128;              // 128*128 bf16 = 32 KB

    const int Nn = in_sizes[0];   // 20000

    prep_kernel<<<192, 256, 0, stream>>>(W1, W2, W1t, W2t);
    const int grid = (Nn + 7) / 8;
    ppagg_mfma<<<grid, 256, 0, stream>>>(nodes, neigh, degrees, u2e,
                                         W1t, W2t, b1, b2, W3, b3, out, Nn);
}